// Round 5
// baseline (407.311 us; speedup 1.0000x reference)
//
#include <hip/hip_runtime.h>

typedef _Float16 half_t;
typedef _Float16 h8 __attribute__((ext_vector_type(8)));
typedef _Float16 h4 __attribute__((ext_vector_type(4)));
typedef float f4 __attribute__((ext_vector_type(4)));

#define DEV __device__ __forceinline__

constexpr int Bc = 2, Sc = 4096, Ec = 1024, Hc = 16, Dc = 64, Wc = 256, Gc = 64;
constexpr float QSCALE = 0.125f;     // 1/sqrt(D)
constexpr float NEGV = -1e9f;

DEV f4 mfma16(h8 a, h8 b, f4 c) {
  return __builtin_amdgcn_mfma_f32_16x16x32_f16(a, b, c, 0, 0, 0);
}

DEV void gl_lds16(const half_t* g, half_t* l) {
  __builtin_amdgcn_global_load_lds((const __attribute__((address_space(1))) void*)g,
                                   (__attribute__((address_space(3))) void*)l, 16, 0, 0);
}

// Raw barrier (no implicit vmcnt(0)/lgkmcnt(0) drain) + counted vmcnt wait.
#define BARx()  asm volatile("s_barrier" ::: "memory")
#define VMW(N)  asm volatile("s_waitcnt vmcnt(" #N ")" ::: "memory")
#define LGKM0() asm volatile("s_waitcnt lgkmcnt(0)" ::: "memory")

// ---------------- prep: x->f16  +  7 weight transposes, one dispatch ----------------
__global__ void prep(const float* __restrict__ x,
                     const float* __restrict__ Wq, const float* __restrict__ Wk,
                     const float* __restrict__ Wv, const float* __restrict__ Wkg,
                     const float* __restrict__ Wvg, const float* __restrict__ Wqg,
                     const float* __restrict__ Wo,
                     half_t* __restrict__ xh, half_t* __restrict__ Wcat,
                     half_t* __restrict__ WtO) {
  __shared__ float tile[64][65];
  const int bx = blockIdx.x;
  if (bx < 8192) {
    int i = bx * 256 + threadIdx.x;
    float4 v = ((const float4*)x)[i];
    h4 o;
    o[0] = (half_t)v.x; o[1] = (half_t)v.y; o[2] = (half_t)v.z; o[3] = (half_t)v.w;
    ((h4*)xh)[i] = o;
    return;
  }
  const int widx = bx - 8192;
  const int y = widx >> 8;         // 0..6: q,k,v,kg,vg,qg,o
  const int xb = widx & 255;
  const float* W = (y == 0) ? Wq : (y == 1) ? Wk : (y == 2) ? Wv :
                   (y == 3) ? Wkg : (y == 4) ? Wvg : (y == 5) ? Wqg : Wo;
  half_t* Wt = (y < 6) ? (Wcat + (size_t)y * Ec * Ec) : WtO;
  const int bxt = xb & 15, byt = xb >> 4;
  const int tx = threadIdx.x & 63, ty = threadIdx.x >> 6;
  const int n0 = bxt * 64, k0 = byt * 64;
#pragma unroll
  for (int i = 0; i < 16; ++i) {
    int k = ty + i * 4;
    tile[k][tx] = W[(size_t)(k0 + k) * Ec + n0 + tx];
  }
  __syncthreads();
#pragma unroll
  for (int i = 0; i < 16; ++i) {
    int n = ty + i * 4;
    Wt[(size_t)(n0 + n) * Ec + k0 + tx] = (half_t)tile[tx][n];
  }
}

// ------ fused projection GEMM: m201-template 256x256, BK=64, 8 waves, 4-phase/K-tile ------
// grid (24,33): x<20,y<32 main (XCD = x%8 since 24%8==0 -> B col-panel L2-pinned;
// each col-tile's 32 row-blocks fill one XCD per round). x in 20..23 dummy-exit.
// y==32,x<8: qg path (128 gathered rows x 128 cols), simple sync loop.
// LDS 128KB = 2 dbuf x 2 K-half x (A 256x32 + B 256x32) f16. 1 blk/CU, 8 waves.
// Waves 2M x 4N, per-wave C = 128x64. Per K-tile 4 phases (kappa, m-half):
//   {ds_read A4 [+B4] ; stage 1 half (2 gl_lds) ; [VMW] ; s_barrier ; lgkmcnt(0) ;
//    setprio(1) 16xMFMA setprio(0) ; s_barrier}
// vmcnt ledger (2 loads/half/wave): P1 stages kt+1{Ak0,Bk0}; P2 stages Ak1, VMW(6)
// retires kt{Ak1,Bk1}; P3 stages Bk1; P4 VMW(4) retires kt+1{Ak0,Bk0}. Every half
// gets >=4 phases (~1000cyc) in flight > ~900cyc HBM latency. Never vmcnt(0) in loop.
// Per-kappa-half LDS arrays have 64B row stride -> proven 0-conflict slot swizzle
// (store chunk c of row r at slot c ^ ((r>>1)&3); read slot qd ^ ((r>>1)&3)).
__global__ __launch_bounds__(512, 2) void gemm_proj(const half_t* __restrict__ A,
                                                    const half_t* __restrict__ Bt,
                                                    const float* __restrict__ bq,
                                                    const float* __restrict__ bk,
                                                    const float* __restrict__ bv,
                                                    const float* __restrict__ bkg,
                                                    const float* __restrict__ bvg,
                                                    const float* __restrict__ bqg,
                                                    half_t* __restrict__ qh, half_t* __restrict__ kh,
                                                    half_t* __restrict__ vt, half_t* __restrict__ kgh,
                                                    half_t* __restrict__ vgt, half_t* __restrict__ qgh) {
  __shared__ __align__(16) half_t Ash[4][8192];   // [buf*2 + kappa], 16KB each = 64KB
  __shared__ __align__(16) half_t Bsh[4][8192];   // 64KB
  const int x = blockIdx.x, y = blockIdx.y;
  const bool qgblk = (y == 32);
  if (!qgblk && x >= 20) return;
  if (qgblk && x >= 8) return;
  const int tid = threadIdx.x;
  const int wv = tid >> 6, lane = tid & 63;
  const int mr = lane & 15, qd = lane >> 4;

  if (qgblk) {
    // ---- qg: 128 gathered rows x 128 cols, BK=64, plain __syncthreads loop ----
    const int col0 = 5 * Ec + x * 128;
    const int wm = wv >> 2, wn = wv & 3;          // per-wave 64 x 32
    const int r = tid >> 2, s = tid & 3;
    const int c = s ^ ((r >> 1) & 3);
    const int ar = (r < 64) ? r : 4032 + r;       // gathered rows (batch0/1, s<G)
    const half_t* sAq = A + (size_t)ar * Ec + c * 8;
    const half_t* sBq = Bt + (size_t)(col0 + r) * Ec + c * 8;
    const int dq = tid * 8;
    int aoq[4], boq[2];
#pragma unroll
    for (int mt = 0; mt < 4; ++mt) {
      const int rr = wm * 64 + mt * 16 + mr;
      aoq[mt] = ((rr << 2) | (qd ^ ((rr >> 1) & 3))) * 8;
    }
#pragma unroll
    for (int nt = 0; nt < 2; ++nt) {
      const int rr = wn * 32 + nt * 16 + mr;
      boq[nt] = ((rr << 2) | (qd ^ ((rr >> 1) & 3))) * 8;
    }
    f4 accq[4][2] = {};
    for (int kt = 0; kt < 16; ++kt) {
      const int kb = kt * 64;
      gl_lds16(sAq + kb,      &Ash[0][0] + dq);
      gl_lds16(sAq + kb + 32, &Ash[1][0] + dq);
      gl_lds16(sBq + kb,      &Bsh[0][0] + dq);
      gl_lds16(sBq + kb + 32, &Bsh[1][0] + dq);
      __syncthreads();
#pragma unroll
      for (int kap = 0; kap < 2; ++kap) {
        h8 afq[4], bfq[2];
#pragma unroll
        for (int mt = 0; mt < 4; ++mt) afq[mt] = *(const h8*)(&Ash[kap][0] + aoq[mt]);
#pragma unroll
        for (int nt = 0; nt < 2; ++nt) bfq[nt] = *(const h8*)(&Bsh[kap][0] + boq[nt]);
#pragma unroll
        for (int mt = 0; mt < 4; ++mt)
#pragma unroll
          for (int nt = 0; nt < 2; ++nt)
            accq[mt][nt] = mfma16(afq[mt], bfq[nt], accq[mt][nt]);
      }
      __syncthreads();
    }
#pragma unroll
    for (int mt = 0; mt < 4; ++mt)
#pragma unroll
      for (int nt = 0; nt < 2; ++nt) {
        const int C = col0 + wn * 32 + nt * 16 + mr;
        const int c1 = C & 1023, hh = c1 >> 6, d = c1 & 63;
        const float bval = bqg[c1];
        const int Rb = wm * 64 + mt * 16 + qd * 4;
#pragma unroll
        for (int r2 = 0; r2 < 4; ++r2) {
          const int R = Rb + r2;
          const int b = R >> 6, s2 = R & 63;
          qgh[((size_t)(b * Hc + hh) * Gc + s2) * Dc + d] =
              (half_t)((accq[mt][nt][r2] + bval) * QSCALE);
        }
      }
    return;
  }

  // ---- main path ----
  const int wv_m = wv >> 2, wv_n = wv & 3;        // 2M x 4N, per-wave 128x64
  const int col0 = x * 256, row0 = y * 256;
  const int g = col0 >> 10;                       // 256 | 1024 -> uniform per block

  // staging sources (pre-swizzled global chunk, linear LDS dest), 2 calls per half
  const half_t* sA[2];
  const half_t* sB[2];
  int dsto[2];
#pragma unroll
  for (int j = 0; j < 2; ++j) {
    const int idx = j * 512 + tid;                // 1024 slots = 256 rows x 4
    const int r = idx >> 2, s = idx & 3;
    const int c = s ^ ((r >> 1) & 3);
    sA[j] = A + (size_t)(row0 + r) * Ec + c * 8;
    sB[j] = Bt + (size_t)(col0 + r) * Ec + c * 8;
    dsto[j] = idx * 8;
  }
  // LDS read offsets (proven 0-conflict pattern, per kappa-half array)
  int aoff[8], boff[4];
#pragma unroll
  for (int mt = 0; mt < 8; ++mt) {
    const int r = wv_m * 128 + mt * 16 + mr;
    aoff[mt] = ((r << 2) | (qd ^ ((r >> 1) & 3))) * 8;
  }
#pragma unroll
  for (int nt = 0; nt < 4; ++nt) {
    const int r = wv_n * 64 + nt * 16 + mr;
    boff[nt] = ((r << 2) | (qd ^ ((r >> 1) & 3))) * 8;
  }

  f4 acc[8][4] = {};
  h8 bf[4];

  auto stgA = [&](int pk, int kb) {
    half_t* d = &Ash[pk][0];
    gl_lds16(sA[0] + kb, d + dsto[0]);
    gl_lds16(sA[1] + kb, d + dsto[1]);
  };
  auto stgB = [&](int pk, int kb) {
    half_t* d = &Bsh[pk][0];
    gl_lds16(sB[0] + kb, d + dsto[0]);
    gl_lds16(sB[1] + kb, d + dsto[1]);
  };
  auto rdA = [&](h8* af, int pk, int MT0) {
    const half_t* ab = &Ash[pk][0];
#pragma unroll
    for (int mt = 0; mt < 4; ++mt) af[mt] = *(const h8*)(ab + aoff[MT0 + mt]);
  };
  auto rdB = [&](int pk) {
    const half_t* bb = &Bsh[pk][0];
#pragma unroll
    for (int nt = 0; nt < 4; ++nt) bf[nt] = *(const h8*)(bb + boff[nt]);
  };
  auto mm = [&](const h8* af, int MT0) {
    __builtin_amdgcn_s_setprio(1);
#pragma unroll
    for (int mt = 0; mt < 4; ++mt)
#pragma unroll
      for (int nt = 0; nt < 4; ++nt)
        acc[MT0 + mt][nt] = mfma16(af[mt], bf[nt], acc[MT0 + mt][nt]);
    __builtin_amdgcn_s_setprio(0);
  };

  // prologue: stage kt0 {Ak0,Bk0,Ak1,Bk1}; VMW(4) retires k0 halves; barrier
  stgA(0, 0);  stgB(0, 0);
  stgA(1, 32); stgB(1, 32);
  VMW(4);
  BARx();

#pragma unroll 1
  for (int kt = 0; kt < 15; ++kt) {
    const int p = (kt & 1) * 2, pn = ((kt + 1) & 1) * 2;
    const int kn = (kt + 1) * 64;
    h8 af[4];
    // P1: kappa0, m0-3 ; stage kt+1 Ak0,Bk0
    rdB(p); rdA(af, p, 0);
    stgA(pn, kn); stgB(pn, kn);
    BARx(); LGKM0();
    mm(af, 0);
    BARx();
    // P2: kappa0, m4-7 ; stage kt+1 Ak1 ; VMW(6) retires kt's k1 halves
    rdA(af, p, 4);
    stgA(pn + 1, kn + 32);
    VMW(6);
    BARx(); LGKM0();
    mm(af, 4);
    BARx();
    // P3: kappa1, m0-3 ; stage kt+1 Bk1
    rdB(p + 1); rdA(af, p + 1, 0);
    stgB(pn + 1, kn + 32);
    BARx(); LGKM0();
    mm(af, 0);
    BARx();
    // P4: kappa1, m4-7 ; VMW(4) retires kt+1's k0 halves
    rdA(af, p + 1, 4);
    VMW(4);
    BARx(); LGKM0();
    mm(af, 4);
    BARx();
  }
  // kt=15 peeled (buf 1, pk 2/3): no staging; drain k1 at P2
  {
    h8 af[4];
    rdB(2); rdA(af, 2, 0);
    BARx(); LGKM0();
    mm(af, 0);
    BARx();
    rdA(af, 2, 4);
    VMW(0);
    BARx(); LGKM0();
    mm(af, 4);
    BARx();
    rdB(3); rdA(af, 3, 0);
    BARx(); LGKM0();
    mm(af, 0);
    BARx();
    rdA(af, 3, 4);
    LGKM0();
    mm(af, 4);
  }

  // ---- scattered epilogue stores; g uniform per block (0..4) ----
  const float* bptr = (g == 0) ? bq : (g == 1) ? bk : (g == 2) ? bv :
                      (g == 3) ? bkg : bvg;
#pragma unroll
  for (int mt = 0; mt < 8; ++mt) {
#pragma unroll
    for (int nt = 0; nt < 4; ++nt) {
      const int C = col0 + wv_n * 64 + nt * 16 + mr;
      const int c1 = C & 1023, hh = c1 >> 6, d = c1 & 63;
      const float bval = bptr[c1];
      const int Rbase = row0 + wv_m * 128 + mt * 16 + qd * 4;
      f4 a = acc[mt][nt];
      if (g == 2 || g == 4) {  // transposed (B,H,D,S): 4 rows contiguous in S
        half_t* O = (g == 2) ? vt : vgt;
        int b = Rbase >> 12, s = Rbase & 4095;
        h4 pk;
#pragma unroll
        for (int r = 0; r < 4; ++r) pk[r] = (half_t)(a[r] + bval);
        *(h4*)(O + ((size_t)(b * Hc + hh) * Dc + d) * Sc + s) = pk;
      } else {                 // (B,H,S,D), q scaled
        half_t* O = (g == 0) ? qh : (g == 1) ? kh : kgh;
        const float scale = (g == 0) ? QSCALE : 1.0f;
#pragma unroll
        for (int r = 0; r < 4; ++r) {
          int R = Rbase + r;
          int b = R >> 12, s = R & 4095;
          O[((size_t)(b * Hc + hh) * Sc + s) * Dc + d] = (half_t)((a[r] + bval) * scale);
        }
      }
    }
  }
}

// ---------------- output GEMM, BK=32: mfma16 + unroll-3 triple-buffer (R4) ----------------
__global__ __launch_bounds__(256, 3) void gemm_out(const half_t* __restrict__ A,
                                                   const half_t* __restrict__ Bt,
                                                   const float* __restrict__ bias,
                                                   float* __restrict__ O) {
  __shared__ __align__(16) half_t Ash[3][4096];
  __shared__ __align__(16) half_t Bsh[3][4096];
  const int tid = threadIdx.x;
  const int wv = tid >> 6, lane = tid & 63;
  const int mr = lane & 15, qd = lane >> 4;
  const int wv_m = wv >> 1, wv_n = wv & 1;
  const int col0 = blockIdx.x * 128;
  const int row0 = blockIdx.y * 128;

  const half_t* sA[2];
  const half_t* sB[2];
  int dsto[2];
#pragma unroll
  for (int i = 0; i < 2; ++i) {
    const int slot = wv * 128 + i * 64 + lane;
    const int r = slot >> 2;
    const int kc = (slot & 3) ^ ((r >> 1) & 3);
    sA[i] = A + (size_t)(row0 + r) * Ec + kc * 8;
    sB[i] = Bt + (size_t)(col0 + r) * Ec + kc * 8;
    dsto[i] = (wv * 128 + i * 64) * 8;
  }
  int aoff[4], boff[4];
#pragma unroll
  for (int mt = 0; mt < 4; ++mt) {
    const int r = wv_m * 64 + mt * 16 + mr;
    aoff[mt] = ((r << 2) | (qd ^ ((r >> 1) & 3))) * 8;
  }
#pragma unroll
  for (int nt = 0; nt < 4; ++nt) {
    const int r = wv_n * 64 + nt * 16 + mr;
    boff[nt] = ((r << 2) | (qd ^ ((r >> 1) & 3))) * 8;
  }

  f4 acc[4][4] = {};

  auto stage = [&](half_t* da, half_t* db, int k0) {
#pragma unroll
    for (int i = 0; i < 2; ++i) {
      gl_lds16(sA[i] + k0, da + dsto[i]);
      gl_lds16(sB[i] + k0, db + dsto[i]);
    }
  };
  auto compute = [&](const half_t* ba, const half_t* bb) {
    h8 af[4], bf[4];
#pragma unroll
    for (int mt = 0; mt < 4; ++mt) af[mt] = *(const h8*)(ba + aoff[mt]);
#pragma unroll
    for (int nt = 0; nt < 4; ++nt) bf[nt] = *(const h8*)(bb + boff[nt]);
    __builtin_amdgcn_s_setprio(1);
#pragma unroll
    for (int mt = 0; mt < 4; ++mt)
#pragma unroll
      for (int nt = 0; nt < 4; ++nt)
        acc[mt][nt] = mfma16(af[mt], bf[nt], acc[mt][nt]);
    __builtin_amdgcn_s_setprio(0);
  };

  stage(&Ash[0][0], &Bsh[0][0], 0);
  stage(&Ash[1][0], &Bsh[1][0], 32);
  VMW(4);
  BARx();

#pragma unroll 1
  for (int it = 0; it < 10; ++it) {
    const int kk = it * 96;
    stage(&Ash[2][0], &Bsh[2][0], kk + 64);
    compute(&Ash[0][0], &Bsh[0][0]);
    VMW(4); BARx();
    stage(&Ash[0][0], &Bsh[0][0], kk + 96);
    compute(&Ash[1][0], &Bsh[1][0]);
    VMW(4); BARx();
    stage(&Ash[1][0], &Bsh[1][0], kk + 128);
    compute(&Ash[2][0], &Bsh[2][0]);
    VMW(4); BARx();
  }
  compute(&Ash[0][0], &Bsh[0][0]);
  VMW(0);
  BARx();
  compute(&Ash[1][0], &Bsh[1][0]);

#pragma unroll
  for (int mt = 0; mt < 4; ++mt) {
#pragma unroll
    for (int nt = 0; nt < 4; ++nt) {
      const int C = col0 + wv_n * 64 + nt * 16 + mr;
      const float bval = bias[C];
      const int Rbase = row0 + wv_m * 64 + mt * 16 + qd * 4;
      f4 a = acc[mt][nt];
#pragma unroll
      for (int r = 0; r < 4; ++r)
        O[(size_t)(Rbase + r) * Ec + C] = a[r] + bval;
    }
  }
}

// ---------------- windowed + global-key attention (flash-style, LDS-staged) ----------------
__global__ __launch_bounds__(256) void win_attn(const half_t* __restrict__ qh,
                                                const half_t* __restrict__ kh,
                                                const half_t* __restrict__ vt,
                                                half_t* __restrict__ ctx) {
  constexpr int PST = 88;
  __shared__ __align__(16) half_t Kb[2][64 * 64];
  __shared__ __align__(16) half_t Vb[2][64 * 64];
  __shared__ __align__(16) half_t Pl[4][16 * PST];
  const int bid = blockIdx.x;
  const int qc = bid & 15, h = (bid >> 4) & 15, b = bid >> 8;
  const int qs = qc << 8;
  const int tid = threadIdx.x, wv = tid >> 6, lane = tid & 63;
  const int mr = lane & 15, qd = lane >> 4;
  const int qw = qs + wv * 64;
  const size_t bh = (size_t)(b * Hc + h);
  const half_t* qb = qh + bh * Sc * Dc;
  const half_t* kb = kh + bh * Sc * Dc;
  const half_t* vb = vt + bh * Dc * Sc;
  half_t* Pw = &Pl[wv][0];

  h8 qf[4][2];
#pragma unroll
  for (int qt = 0; qt < 4; ++qt) {
    const half_t* qrow = qb + (size_t)(qw + qt * 16 + mr) * Dc;
    qf[qt][0] = *(const h8*)(qrow + qd * 8);
    qf[qt][1] = *(const h8*)(qrow + 32 + qd * 8);
  }

  int tiles[14];
  int nT = 0;
  tiles[nT++] = 0;
  {
    int lo = qs - Wc; if (lo < Gc) lo = Gc;
    int hi2 = qs + 448; if (hi2 > Sc - 64) hi2 = Sc - 64;
    for (int kp0 = lo; kp0 <= hi2; kp0 += 64) tiles[nT++] = kp0;
  }

  auto stage = [&](int kp0, int bi) {
#pragma unroll
    for (int i = 0; i < 2; ++i) {
      const int seg = wv * 2 + i;
      const int s = seg * 64 + lane;
      const int r = s >> 3;
      const int kc = (s & 7) ^ (r & 7);
      gl_lds16(kb + (size_t)(kp0 + r) * Dc + kc * 8, &Kb[bi][seg * 512]);
      gl_lds16(vb + (size_t)r * Sc + kp0 + kc * 8, &Vb[bi][seg * 512]);
    }
  };

  float m_run[4], l_run[4];
  f4 acc[4][4] = {};
#pragma unroll
  for (int qt = 0; qt < 4; ++qt) { m_run[qt] = -1e30f; l_run[qt] = 0.f; }

  stage(tiles[0], 0);

  for (int t = 0; t < nT; ++t) {
    __syncthreads();
    if (t + 1 < nT) stage(tiles[t + 1], (t + 1) & 1);
    const int kp0 = tiles[t];
    if (t > 0 && (kp0 > qw + 319 || kp0 + 63 < qw - Wc)) continue;

    const half_t* BK = Kb[t & 1];
    const half_t* BV = Vb[t & 1];
    h8 kf[4][2], vf[4][2];
#pragma unroll
    for (int mt = 0; mt < 4; ++mt) {
      const int row = mt * 16 + mr, r7 = row & 7;
      kf[mt][0] = *(const h8*)(BK + (size_t)(row * 8 + (qd ^ r7)) * 8);
      kf[mt][1] = *(const h8*)(BK + (size_t)(row * 8 + ((qd + 4) ^ r7)) * 8);
      vf[mt][0] = *(const h8*)(BV + (size_t)(row * 8 + (qd ^ r7)) * 8);
      vf[mt][1] = *(const h8*)(BV + (size_t)(row * 8 + ((qd + 4) ^ r7)) * 8);
    }
    const bool nomask = (t == 0) || (kp0 >= qw - 193 && kp0 <= qw + 193);

#pragma unroll
    for (int qt = 0; qt < 4; ++qt) {
      f4 sa[4];
#pragma unroll
      for (int mt = 0; mt < 4; ++mt) {
        f4 s = {};
        s = mfma16(kf[mt][0], qf[qt][0], s);
        s = mfma16(kf[mt][1], qf[qt][1], s);
        sa[mt] = s;
      }
      const int q = qw + qt * 16 + mr;
      if (!nomask) {
#pragma unroll
        for (int mt = 0; mt < 4; ++mt)
#pragma unroll
          for (int r = 0; r < 4; ++r) {
            const int kp = kp0 + mt * 16 + qd * 4 + r;
            if (kp < q - Wc || kp > q + Wc) sa[mt][r] = NEGV;
          }
      }
      float tm = -1e30f;
#pragma unroll
      for (int mt = 0; mt < 4; ++mt)
#pragma unroll
        for (int r = 0; r < 4; ++r) tm = fmaxf(tm, sa[mt][r]);
      tm = fmaxf(tm, __shfl_xor(tm, 16));
      tm = fmaxf(tm, __shfl_xor(tm, 32));
      const float mnew = fmaxf(m_run[qt], tm);
      const float alpha = __expf(m_run[qt] - mnew);
      m_run[qt] = mnew;
      float psum = 0.0f;
#pragma unroll
      for (int mt = 0; mt < 4; ++mt) {
        h4 pk;
#pragma unroll
        for (int r = 0; r < 4; ++r) {
          const float p = __expf(sa[mt][r] - mnew);
          psum += p;
          pk[r] = (half_t)p;
        }
        *(h4*)(Pw + mr * PST + mt * 16 + qd * 4) = pk;
      }
      psum += __shfl_xor(psum, 16);
      psum += __shfl_xor(psum, 32);
      l_run[qt] = l_run[qt] * alpha + psum;
#pragma unroll
      for (int mt = 0; mt < 4; ++mt)
#pragma unroll
        for (int r = 0; r < 4; ++r) acc[qt][mt][r] *= alpha;
      const h8 p0 = *(const h8*)(Pw + mr * PST + qd * 8);
      const h8 p1 = *(const h8*)(Pw + mr * PST + 32 + qd * 8);
#pragma unroll
      for (int mt = 0; mt < 4; ++mt) {
        acc[qt][mt] = mfma16(vf[mt][0], p0, acc[qt][mt]);
        acc[qt][mt] = mfma16(vf[mt][1], p1, acc[qt][mt]);
      }
    }
  }

#pragma unroll
  for (int qt = 0; qt < 4; ++qt) {
    const float inv = 1.0f / l_run[qt];
    const int q = qw + qt * 16 + mr;
    half_t* crow = ctx + ((size_t)(b * Sc) + q) * Ec + h * Dc;
#pragma unroll
    for (int mt = 0; mt < 4; ++mt) {
      h4 pk;
#pragma unroll
      for (int r = 0; r < 4; ++r) pk[r] = (half_t)(acc[qt][mt][r] * inv);
      *(h4*)(crow + mt * 16 + qd * 4) = pk;
    }
  }
}

// ---------------- global-query attention: flash-decoding split over S ----------------
__global__ __launch_bounds__(256) void gq_part(const half_t* __restrict__ qgh,
                                               const half_t* __restrict__ kgh,
                                               const half_t* __restrict__ vgt,
                                               float* __restrict__ pm,
                                               float* __restrict__ pl,
                                               float* __restrict__ pacc) {
  constexpr int PST = 88;
  __shared__ __align__(16) half_t Pl[4][16 * PST];
  const int ch = blockIdx.x & 7, h = (blockIdx.x >> 3) & 15, b = blockIdx.x >> 7;
  const int tid = threadIdx.x, wv = tid >> 6, lane = tid & 63;
  const int mr = lane & 15, qd = lane >> 4;
  const size_t bh = (size_t)(b * Hc + h);
  const half_t* qb = qgh + bh * Gc * Dc;
  const half_t* kb = kgh + bh * Sc * Dc;
  const half_t* vb = vgt + bh * Dc * Sc;
  half_t* Pw = &Pl[wv][0];

  const int qrow = wv * 16 + mr;
  const h8 qf0 = *(const h8*)(qb + (size_t)qrow * Dc + qd * 8);
  const h8 qf1 = *(const h8*)(qb + (size_t)qrow * Dc + 32 + qd * 8);

  float m_run = -1e30f, l_run = 0.f;
  f4 acc[4] = {};

  for (int t = 0; t < 8; ++t) {
    const int kp0 = ch * 512 + t * 64;
    f4 sa[4];
#pragma unroll
    for (int mt = 0; mt < 4; ++mt) {
      const int kp = kp0 + mt * 16 + mr;
      h8 kf0 = *(const h8*)(kb + (size_t)kp * Dc + qd * 8);
      h8 kf1 = *(const h8*)(kb + (size_t)kp * Dc + 32 + qd * 8);
      f4 s = {};
      s = mfma16(kf0, qf0, s);
      s = mfma16(kf1, qf1, s);
      sa[mt] = s;
    }
    float tm = -1e30f;
#pragma unroll
    for (int mt = 0; mt < 4; ++mt)
#pragma unroll
      for (int r = 0; r < 4; ++r) tm = fmaxf(tm, sa[mt][r]);
    tm = fmaxf(tm, __shfl_xor(tm, 16));
    tm = fmaxf(tm, __shfl_xor(tm, 32));
    const float mnew = fmaxf(m_run, tm);
    const float alpha = __expf(m_run - mnew);
    m_run = mnew;
    float psum = 0.0f;
#pragma unroll
    for (int mt = 0; mt < 4; ++mt) {
      h4 pk;
#pragma unroll
      for (int r = 0; r < 4; ++r) {
        const float p = __expf(sa[mt][r] - mnew);
        psum += p;
        pk[r] = (half_t)p;
      }
      *(h4*)(Pw + mr * PST + mt * 16 + qd * 4) = pk;
    }
    psum += __shfl_xor(psum, 16);
    psum += __shfl_xor(psum, 32);
    l_run = l_run * alpha + psum;
#pragma unroll
    for (int mt = 0; mt < 4; ++mt)
#pragma unroll
      for (int r = 0; r < 4; ++r) acc[mt][r] *= alpha;
    const h8 p0 = *(const h8*)(Pw + mr * PST + qd * 8);
    const h8 p1 = *(const h8*)(Pw + mr * PST + 32 + qd * 8);
#pragma unroll
    for (int mt = 0; mt < 4; ++mt) {
      const h8 vf0 = *(const h8*)(vb + (size_t)(mt * 16 + mr) * Sc + kp0 + qd * 8);
      const h8 vf1 = *(const h8*)(vb + (size_t)(mt * 16 + mr) * Sc + kp0 + 32 + qd * 8);
      acc[mt] = mfma16(vf0, p0, acc[mt]);
      acc[mt] = mfma16(vf1, p1, acc[mt]);
    }
  }

  const size_t pidx = (bh * 8 + ch) * Gc + qrow;
  if (qd == 0) { pm[pidx] = m_run; pl[pidx] = l_run; }
  float* pa = pacc + pidx * Dc;
#pragma unroll
  for (int mt = 0; mt < 4; ++mt)
#pragma unroll
    for (int r = 0; r < 4; ++r)
      pa[mt * 16 + qd * 4 + r] = acc[mt][r];
}

// gq_combine: grid = B*H; thread (q = tid>>2, 16 d's at dg=(tid&3)*16) merges 8 chunks.
__global__ __launch_bounds__(256) void gq_combine(const float* __restrict__ pm,
                                                  const float* __restrict__ pl,
                                                  const float* __restrict__ pacc,
                                                  half_t* __restrict__ ctx) {
  const int h = blockIdx.x & 15, b = blockIdx.x >> 4;
  const size_t bh = (size_t)(b * Hc + h);
  const int q = threadIdx.x >> 2, dg = (threadIdx.x & 3) * 16;
  float m[8];
  float M = -1e30f;
#pragma unroll
  for (int c = 0; c < 8; ++c) {
    m[c] = pm[(bh * 8 + c) * Gc + q];
    M = fmaxf(M, m[c]);
  }
  float denom = 0.f, num[16] = {};
#pragma unroll
  for (int c = 0; c < 8; ++c) {
    const float w = __expf(m[c] - M);
    denom += w * pl[(bh * 8 + c) * Gc + q];
    const float* pa = pacc + ((bh * 8 + c) * Gc + q) * Dc + dg;
#pragma unroll
    for (int j = 0; j < 16; ++j) num[j] += w * pa[j];
  }
  const float inv = 1.0f / denom;
  half_t* crow = ctx + ((size_t)(b * Sc) + q) * Ec + h * Dc + dg;
#pragma unroll
  for (int j = 0; j < 16; ++j) crow[j] = (half_t)(num[j] * inv);
}

// ---------------- host launch ----------------

extern "C" void kernel_launch(void* const* d_in, const int* in_sizes, int n_in,
                              void* d_out, int out_size, void* d_ws, size_t ws_size,
                              hipStream_t stream) {
  const float* x   = (const float*)d_in[0];
  const float* Wq  = (const float*)d_in[2];
  const float* bq  = (const float*)d_in[3];
  const float* Wk  = (const float*)d_in[4];
  const float* bk  = (const float*)d_in[5];
  const float* Wv  = (const float*)d_in[6];
  const float* bv  = (const float*)d_in[7];
  const float* Wqg = (const float*)d_in[8];
  const float* bqg = (const float*)d_in[9];
  const float* Wkg = (const float*)d_in[10];
  const float* bkg = (const float*)d_in[11];
  const float* Wvg = (const float*)d_in[12];
  const float* bvg = (const float*)d_in[13];
  const float* Wo  = (const float*)d_in[14];
  const float* bo  = (const float*)d_in[15];
  float* out = (float*)d_out;

  char* ws = (char*)d_ws;
  size_t off = 0;
  auto alloc = [&](size_t bytes) {
    void* p = ws + off;
    off = (off + bytes + 255) & ~(size_t)255;
    return p;
  };
  const size_t BSE2 = (size_t)Bc * Sc * Ec * 2;
  const size_t W2 = (size_t)Ec * Ec * 2;
  half_t* xh   = (half_t*)alloc(BSE2);
  half_t* Wcat = (half_t*)alloc(W2 * 6);   // q,k,v,kg,vg,qg transposed f16
  half_t* WtO  = (half_t*)alloc(W2);
  half_t* qh   = (half_t*)alloc(BSE2);     // (B,H,S,D) scaled
  half_t* kh   = (half_t*)alloc(BSE2);     // (B,H,S,D)
  half_t* vt   = (half_t*)alloc(BSE2);     // (B,H,D,S)
  half_t* kgh  = (half_t*)alloc(BSE2);     // (B,H,S,D)
  half_t* vgt  = (half_t*)alloc(BSE2);     // (B,H,D,S)
  half_t* qgh  = (half_t*)alloc((size_t)Bc * Hc * Gc * Dc * 2);
  half_t* ctx  = (half_t*)alloc(BSE2);
  float*  pm   = (float*)alloc((size_t)Bc * Hc * 8 * Gc * 4);
  float*  pl   = (float*)alloc((size_t)Bc * Hc * 8 * Gc * 4);
  float*  pacc = (float*)alloc((size_t)Bc * Hc * 8 * Gc * Dc * 4);
  (void)ws_size; (void)in_sizes; (void)n_in; (void)out_size;

  prep<<<8192 + 7 * 256, 256, 0, stream>>>(x, Wq, Wk, Wv, Wkg, Wvg, Wqg, Wo,
                                           xh, Wcat, WtO);

  gemm_proj<<<dim3(24, 33), 512, 0, stream>>>(xh, Wcat, bq, bk, bv, bkg, bvg, bqg,
                                              qh, kh, vt, kgh, vgt, qgh);

  win_attn<<<Bc * Hc * (Sc / 256), 256, 0, stream>>>(qh, kh, vt, ctx);

  gq_part<<<Bc * Hc * 8, 256, 0, stream>>>(qgh, kgh, vgt, pm, pl, pacc);
  gq_combine<<<Bc * Hc, 256, 0, stream>>>(pm, pl, pacc, ctx);

  gemm_out<<<dim3(8, 64), 256, 0, stream>>>(ctx, WtO, bo, out);
}

// Round 6
// 394.240 us; speedup vs baseline: 1.0332x; 1.0332x over previous
//
#include <hip/hip_runtime.h>

typedef _Float16 half_t;
typedef _Float16 h8 __attribute__((ext_vector_type(8)));
typedef _Float16 h4 __attribute__((ext_vector_type(4)));
typedef _Float16 h2 __attribute__((ext_vector_type(2)));
typedef float f4 __attribute__((ext_vector_type(4)));

#define DEV __device__ __forceinline__

constexpr int Bc = 2, Sc = 4096, Ec = 1024, Hc = 16, Dc = 64, Wc = 256, Gc = 64;
constexpr float QSCALE = 0.125f;     // 1/sqrt(D)
constexpr float NEGV = -1e9f;

DEV f4 mfma16(h8 a, h8 b, f4 c) {
  return __builtin_amdgcn_mfma_f32_16x16x32_f16(a, b, c, 0, 0, 0);
}

DEV void gl_lds16(const half_t* g, half_t* l) {
  __builtin_amdgcn_global_load_lds((const __attribute__((address_space(1))) void*)g,
                                   (__attribute__((address_space(3))) void*)l, 16, 0, 0);
}

// Raw barrier (no implicit vmcnt(0)/lgkmcnt(0) drain) + counted vmcnt wait.
#define BARx() asm volatile("s_barrier" ::: "memory")
#define VMW(N) asm volatile("s_waitcnt vmcnt(" #N ")" ::: "memory")

// ---------------- prep: x->f16 (8 elems/thread, h8 stores)  +  7 weight transposes ----------------
__global__ void prep(const float* __restrict__ x,
                     const float* __restrict__ Wq, const float* __restrict__ Wk,
                     const float* __restrict__ Wv, const float* __restrict__ Wkg,
                     const float* __restrict__ Wvg, const float* __restrict__ Wqg,
                     const float* __restrict__ Wo,
                     half_t* __restrict__ xh, half_t* __restrict__ Wcat,
                     half_t* __restrict__ WtO) {
  __shared__ float tile[64][65];
  const int bx = blockIdx.x;
  if (bx < 4096) {
    // 8,388,608 f32 = 4096 blocks x 256 thr x 8 elems
    const int i = bx * 256 + threadIdx.x;
    const float4* x4 = (const float4*)x;
    float4 a = x4[i * 2], b = x4[i * 2 + 1];
    h8 o;
    o[0] = (half_t)a.x; o[1] = (half_t)a.y; o[2] = (half_t)a.z; o[3] = (half_t)a.w;
    o[4] = (half_t)b.x; o[5] = (half_t)b.y; o[6] = (half_t)b.z; o[7] = (half_t)b.w;
    ((h8*)xh)[i] = o;
    return;
  }
  const int widx = bx - 4096;
  const int y = widx >> 8;         // 0..6: q,k,v,kg,vg,qg,o
  const int xb = widx & 255;
  const float* W = (y == 0) ? Wq : (y == 1) ? Wk : (y == 2) ? Wv :
                   (y == 3) ? Wkg : (y == 4) ? Wvg : (y == 5) ? Wqg : Wo;
  half_t* Wt = (y < 6) ? (Wcat + (size_t)y * Ec * Ec) : WtO;
  const int bxt = xb & 15, byt = xb >> 4;
  const int tx = threadIdx.x & 63, ty = threadIdx.x >> 6;
  const int n0 = bxt * 64, k0 = byt * 64;
#pragma unroll
  for (int i = 0; i < 16; ++i) {
    int k = ty + i * 4;
    tile[k][tx] = W[(size_t)(k0 + k) * Ec + n0 + tx];
  }
  __syncthreads();
  // packed h2 writes: thread (tx2,ty2) writes k-pair {2tx2,2tx2+1} of row n.
  // LDS read banks: (2*tx2 + n) % 32 -> 2-way aliasing (free, m136).
  const int tx2 = threadIdx.x & 31, ty2 = threadIdx.x >> 5;
#pragma unroll
  for (int i = 0; i < 8; ++i) {
    const int n = ty2 + i * 8;
    h2 v;
    v[0] = (half_t)tile[2 * tx2][n];
    v[1] = (half_t)tile[2 * tx2 + 1][n];
    *(h2*)(Wt + (size_t)(n0 + n) * Ec + k0 + tx2 * 2) = v;
  }
}

// ------ fused projection GEMM: 256x128 block, 4 waves of 128x64, BK=32 (R4, proven) ------
// Triple-buffer counted-vmcnt, mfma16 with the proven 0-conflict LDS read pattern.
// Per-wave: 12 ds_read_b128 feed 32 MFMA. LDS 72KB -> 2 blocks/CU.
// grid (40,33). y<32: main, rows=y*256, cols=x*128, g=col/1024.
// y==32, x<8: qg over 128 gathered rows (store-guarded).
// grid.x=40 -> XCD = col-tile mod 8 (B panels L2-resident; FETCH ~89MB proven).
__global__ __launch_bounds__(256, 2) void gemm_proj(const half_t* __restrict__ A,
                                                    const half_t* __restrict__ Bt,
                                                    const float* __restrict__ bq,
                                                    const float* __restrict__ bk,
                                                    const float* __restrict__ bv,
                                                    const float* __restrict__ bkg,
                                                    const float* __restrict__ bvg,
                                                    const float* __restrict__ bqg,
                                                    half_t* __restrict__ qh, half_t* __restrict__ kh,
                                                    half_t* __restrict__ vt, half_t* __restrict__ kgh,
                                                    half_t* __restrict__ vgt, half_t* __restrict__ qgh) {
  __shared__ __align__(16) half_t Ash[3][8192];   // 3 x 256x32 f16 = 48 KB
  __shared__ __align__(16) half_t Bsh[3][4096];   // 3 x 128x32 f16 = 24 KB
  const bool qgblk = (blockIdx.y == 32);
  if (qgblk && blockIdx.x >= 8) return;
  const int tid = threadIdx.x;
  const int wv = tid >> 6, lane = tid & 63;
  const int mr = lane & 15, qd = lane >> 4;
  const int wv_m = wv >> 1, wv_n = wv & 1;
  const int col0 = qgblk ? (5 * Ec + (int)blockIdx.x * 128) : (int)blockIdx.x * 128;
  const int row0 = qgblk ? 0 : (int)blockIdx.y * 256;
  const int g = col0 >> 10;

  // staging sources (pre-swizzled global, linear LDS dest): A 4 rounds, B 2 rounds
  const half_t* sA[4];
  const half_t* sB[2];
  int dstoA[4], dstoB[2];
#pragma unroll
  for (int j = 0; j < 4; ++j) {
    const int slot = j * 256 + tid;
    const int r = slot >> 2;
    const int kc = (slot & 3) ^ ((r >> 1) & 3);  // parity-spread swizzle (0 conflicts)
    int ar;
    if (qgblk) { const int rm = r & 127; ar = (rm < 64) ? rm : 4032 + rm; }
    else ar = row0 + r;
    sA[j] = A + (size_t)ar * Ec + kc * 8;
    dstoA[j] = slot * 8;
  }
#pragma unroll
  for (int j = 0; j < 2; ++j) {
    const int slot = j * 256 + tid;
    const int r = slot >> 2;
    const int kc = (slot & 3) ^ ((r >> 1) & 3);
    sB[j] = Bt + (size_t)(col0 + r) * Ec + kc * 8;
    dstoB[j] = slot * 8;
  }
  // LDS read offsets: mfma16 fragments, 16-rows x 4-chunks per read (0-conflict, proven)
  int aoff[8], boff[4];
#pragma unroll
  for (int mt = 0; mt < 8; ++mt) {
    const int r = wv_m * 128 + mt * 16 + mr;
    aoff[mt] = ((r << 2) | (qd ^ ((r >> 1) & 3))) * 8;
  }
#pragma unroll
  for (int nt = 0; nt < 4; ++nt) {
    const int r = wv_n * 64 + nt * 16 + mr;
    boff[nt] = ((r << 2) | (qd ^ ((r >> 1) & 3))) * 8;
  }

  f4 acc[8][4] = {};

  auto stage = [&](half_t* da, half_t* db, int k0) {
#pragma unroll
    for (int j = 0; j < 4; ++j) gl_lds16(sA[j] + k0, da + dstoA[j]);
#pragma unroll
    for (int j = 0; j < 2; ++j) gl_lds16(sB[j] + k0, db + dstoB[j]);
  };
  auto compute = [&](const half_t* ba, const half_t* bb) {
    h8 af[8], bf[4];
#pragma unroll
    for (int mt = 0; mt < 8; ++mt) af[mt] = *(const h8*)(ba + aoff[mt]);
#pragma unroll
    for (int nt = 0; nt < 4; ++nt) bf[nt] = *(const h8*)(bb + boff[nt]);
    __builtin_amdgcn_s_setprio(1);
#pragma unroll
    for (int mt = 0; mt < 8; ++mt)
#pragma unroll
      for (int nt = 0; nt < 4; ++nt)
        acc[mt][nt] = mfma16(af[mt], bf[nt], acc[mt][nt]);
    __builtin_amdgcn_s_setprio(0);
  };

  // prologue: stage kt0, kt1 (6 loads each); VMW(6) retires kt0's; barrier
  stage(&Ash[0][0], &Bsh[0][0], 0);
  stage(&Ash[1][0], &Bsh[1][0], 32);
  VMW(6);
  BARx();

#pragma unroll 1
  for (int it = 0; it < 10; ++it) {
    const int kk = it * 96;
    stage(&Ash[2][0], &Bsh[2][0], kk + 64);    // kt+2 of kt=3it
    compute(&Ash[0][0], &Bsh[0][0]);           // kt=3it
    VMW(6); BARx();                            // kt+1 landed; kt+2 in flight
    stage(&Ash[0][0], &Bsh[0][0], kk + 96);
    compute(&Ash[1][0], &Bsh[1][0]);           // kt=3it+1
    VMW(6); BARx();
    stage(&Ash[1][0], &Bsh[1][0], kk + 128);
    compute(&Ash[2][0], &Bsh[2][0]);           // kt=3it+2
    VMW(6); BARx();
  }
  compute(&Ash[0][0], &Bsh[0][0]);             // kt=30
  VMW(0);
  BARx();
  compute(&Ash[1][0], &Bsh[1][0]);             // kt=31

  // ---- scattered epilogue stores; g uniform per block ----
  const float* bptr = (g == 0) ? bq : (g == 1) ? bk : (g == 2) ? bv :
                      (g == 3) ? bkg : (g == 4) ? bvg : bqg;
#pragma unroll
  for (int mt = 0; mt < 8; ++mt) {
#pragma unroll
    for (int nt = 0; nt < 4; ++nt) {
      const int C = col0 + wv_n * 64 + nt * 16 + mr;
      const int c1 = C & 1023, hh = c1 >> 6, d = c1 & 63;
      const float bval = bptr[c1];
      const int Rbase = row0 + wv_m * 128 + mt * 16 + qd * 4;
      f4 a = acc[mt][nt];
      if (g == 2 || g == 4) {  // transposed (B,H,D,S): 4 rows contiguous in S
        half_t* O = (g == 2) ? vt : vgt;
        int b = Rbase >> 12, s = Rbase & 4095;
        h4 pk;
#pragma unroll
        for (int r = 0; r < 4; ++r) pk[r] = (half_t)(a[r] + bval);
        *(h4*)(O + ((size_t)(b * Hc + hh) * Dc + d) * Sc + s) = pk;
      } else if (g == 5) {     // qg: (B,H,G,D), gathered rows; only R<128 valid
#pragma unroll
        for (int r = 0; r < 4; ++r) {
          int rr = Rbase + r;
          if (rr < 128) {
            int b = rr >> 6, s = rr & 63;
            qgh[((size_t)(b * Hc + hh) * Gc + s) * Dc + d] = (half_t)((a[r] + bval) * QSCALE);
          }
        }
      } else {                 // (B,H,S,D), q scaled
        half_t* O = (g == 0) ? qh : (g == 1) ? kh : kgh;
        const float scale = (g == 0) ? QSCALE : 1.0f;
#pragma unroll
        for (int r = 0; r < 4; ++r) {
          int R = Rbase + r;
          int b = R >> 12, s = R & 4095;
          O[((size_t)(b * Hc + hh) * Sc + s) * Dc + d] = (half_t)((a[r] + bval) * scale);
        }
      }
    }
  }
}

// ---------------- output GEMM, BK=32: mfma16 + unroll-3 triple-buffer (R4) ----------------
__global__ __launch_bounds__(256, 3) void gemm_out(const half_t* __restrict__ A,
                                                   const half_t* __restrict__ Bt,
                                                   const float* __restrict__ bias,
                                                   float* __restrict__ O) {
  __shared__ __align__(16) half_t Ash[3][4096];
  __shared__ __align__(16) half_t Bsh[3][4096];
  const int tid = threadIdx.x;
  const int wv = tid >> 6, lane = tid & 63;
  const int mr = lane & 15, qd = lane >> 4;
  const int wv_m = wv >> 1, wv_n = wv & 1;
  const int col0 = blockIdx.x * 128;
  const int row0 = blockIdx.y * 128;

  const half_t* sA[2];
  const half_t* sB[2];
  int dsto[2];
#pragma unroll
  for (int i = 0; i < 2; ++i) {
    const int slot = wv * 128 + i * 64 + lane;
    const int r = slot >> 2;
    const int kc = (slot & 3) ^ ((r >> 1) & 3);
    sA[i] = A + (size_t)(row0 + r) * Ec + kc * 8;
    sB[i] = Bt + (size_t)(col0 + r) * Ec + kc * 8;
    dsto[i] = (wv * 128 + i * 64) * 8;
  }
  int aoff[4], boff[4];
#pragma unroll
  for (int mt = 0; mt < 4; ++mt) {
    const int r = wv_m * 64 + mt * 16 + mr;
    aoff[mt] = ((r << 2) | (qd ^ ((r >> 1) & 3))) * 8;
  }
#pragma unroll
  for (int nt = 0; nt < 4; ++nt) {
    const int r = wv_n * 64 + nt * 16 + mr;
    boff[nt] = ((r << 2) | (qd ^ ((r >> 1) & 3))) * 8;
  }

  f4 acc[4][4] = {};

  auto stage = [&](half_t* da, half_t* db, int k0) {
#pragma unroll
    for (int i = 0; i < 2; ++i) {
      gl_lds16(sA[i] + k0, da + dsto[i]);
      gl_lds16(sB[i] + k0, db + dsto[i]);
    }
  };
  auto compute = [&](const half_t* ba, const half_t* bb) {
    h8 af[4], bf[4];
#pragma unroll
    for (int mt = 0; mt < 4; ++mt) af[mt] = *(const h8*)(ba + aoff[mt]);
#pragma unroll
    for (int nt = 0; nt < 4; ++nt) bf[nt] = *(const h8*)(bb + boff[nt]);
    __builtin_amdgcn_s_setprio(1);
#pragma unroll
    for (int mt = 0; mt < 4; ++mt)
#pragma unroll
      for (int nt = 0; nt < 4; ++nt)
        acc[mt][nt] = mfma16(af[mt], bf[nt], acc[mt][nt]);
    __builtin_amdgcn_s_setprio(0);
  };

  stage(&Ash[0][0], &Bsh[0][0], 0);
  stage(&Ash[1][0], &Bsh[1][0], 32);
  VMW(4);
  BARx();

#pragma unroll 1
  for (int it = 0; it < 10; ++it) {
    const int kk = it * 96;
    stage(&Ash[2][0], &Bsh[2][0], kk + 64);
    compute(&Ash[0][0], &Bsh[0][0]);
    VMW(4); BARx();
    stage(&Ash[0][0], &Bsh[0][0], kk + 96);
    compute(&Ash[1][0], &Bsh[1][0]);
    VMW(4); BARx();
    stage(&Ash[1][0], &Bsh[1][0], kk + 128);
    compute(&Ash[2][0], &Bsh[2][0]);
    VMW(4); BARx();
  }
  compute(&Ash[0][0], &Bsh[0][0]);
  VMW(0);
  BARx();
  compute(&Ash[1][0], &Bsh[1][0]);

#pragma unroll
  for (int mt = 0; mt < 4; ++mt) {
#pragma unroll
    for (int nt = 0; nt < 4; ++nt) {
      const int C = col0 + wv_n * 64 + nt * 16 + mr;
      const float bval = bias[C];
      const int Rbase = row0 + wv_m * 64 + mt * 16 + qd * 4;
      f4 a = acc[mt][nt];
#pragma unroll
      for (int r = 0; r < 4; ++r)
        O[(size_t)(Rbase + r) * Ec + C] = a[r] + bval;
    }
  }
}

// -------- fused attention: blocks 0..511 windowed (win_attn), 512..767 gq_part --------
// Fusion removes one launch boundary and co-schedules gq's memory-bound waves with
// win_attn's VALU-bound waves. Semantics unchanged: gq_combine later overwrites ctx
// rows s<G that the windowed path wrote.
__global__ __launch_bounds__(256) void attn_fused(const half_t* __restrict__ qh,
                                                  const half_t* __restrict__ kh,
                                                  const half_t* __restrict__ vt,
                                                  const half_t* __restrict__ qgh,
                                                  const half_t* __restrict__ kgh,
                                                  const half_t* __restrict__ vgt,
                                                  half_t* __restrict__ ctx,
                                                  float* __restrict__ pm,
                                                  float* __restrict__ pl,
                                                  float* __restrict__ pacc) {
  constexpr int PST = 88;
  __shared__ __align__(16) half_t Kb[2][64 * 64];
  __shared__ __align__(16) half_t Vb[2][64 * 64];
  __shared__ __align__(16) half_t Pl[4][16 * PST];
  const int bid0 = blockIdx.x;
  const int tid = threadIdx.x, wv = tid >> 6, lane = tid & 63;
  const int mr = lane & 15, qd = lane >> 4;
  half_t* Pw = &Pl[wv][0];

  if (bid0 >= 512) {
    // ---------------- gq_part ----------------
    const int gb = bid0 - 512;
    const int ch = gb & 7, h = (gb >> 3) & 15, b = gb >> 7;
    const size_t bh = (size_t)(b * Hc + h);
    const half_t* qb = qgh + bh * Gc * Dc;
    const half_t* kb = kgh + bh * Sc * Dc;
    const half_t* vb = vgt + bh * Dc * Sc;

    const int qrow = wv * 16 + mr;
    const h8 qf0 = *(const h8*)(qb + (size_t)qrow * Dc + qd * 8);
    const h8 qf1 = *(const h8*)(qb + (size_t)qrow * Dc + 32 + qd * 8);

    float m_run = -1e30f, l_run = 0.f;
    f4 acc[4] = {};

    for (int t = 0; t < 8; ++t) {
      const int kp0 = ch * 512 + t * 64;
      f4 sa[4];
#pragma unroll
      for (int mt = 0; mt < 4; ++mt) {
        const int kp = kp0 + mt * 16 + mr;
        h8 kf0 = *(const h8*)(kb + (size_t)kp * Dc + qd * 8);
        h8 kf1 = *(const h8*)(kb + (size_t)kp * Dc + 32 + qd * 8);
        f4 s = {};
        s = mfma16(kf0, qf0, s);
        s = mfma16(kf1, qf1, s);
        sa[mt] = s;
      }
      float tm = -1e30f;
#pragma unroll
      for (int mt = 0; mt < 4; ++mt)
#pragma unroll
        for (int r = 0; r < 4; ++r) tm = fmaxf(tm, sa[mt][r]);
      tm = fmaxf(tm, __shfl_xor(tm, 16));
      tm = fmaxf(tm, __shfl_xor(tm, 32));
      const float mnew = fmaxf(m_run, tm);
      const float alpha = __expf(m_run - mnew);
      m_run = mnew;
      float psum = 0.0f;
#pragma unroll
      for (int mt = 0; mt < 4; ++mt) {
        h4 pk;
#pragma unroll
        for (int r = 0; r < 4; ++r) {
          const float p = __expf(sa[mt][r] - mnew);
          psum += p;
          pk[r] = (half_t)p;
        }
        *(h4*)(Pw + mr * PST + mt * 16 + qd * 4) = pk;
      }
      psum += __shfl_xor(psum, 16);
      psum += __shfl_xor(psum, 32);
      l_run = l_run * alpha + psum;
#pragma unroll
      for (int mt = 0; mt < 4; ++mt)
#pragma unroll
        for (int r = 0; r < 4; ++r) acc[mt][r] *= alpha;
      const h8 p0 = *(const h8*)(Pw + mr * PST + qd * 8);
      const h8 p1 = *(const h8*)(Pw + mr * PST + 32 + qd * 8);
#pragma unroll
      for (int mt = 0; mt < 4; ++mt) {
        const h8 vf0 = *(const h8*)(vb + (size_t)(mt * 16 + mr) * Sc + kp0 + qd * 8);
        const h8 vf1 = *(const h8*)(vb + (size_t)(mt * 16 + mr) * Sc + kp0 + 32 + qd * 8);
        acc[mt] = mfma16(vf0, p0, acc[mt]);
        acc[mt] = mfma16(vf1, p1, acc[mt]);
      }
    }

    const size_t pidx = (bh * 8 + ch) * Gc + qrow;
    if (qd == 0) { pm[pidx] = m_run; pl[pidx] = l_run; }
    float* pa = pacc + pidx * Dc;
#pragma unroll
    for (int mt = 0; mt < 4; ++mt)
#pragma unroll
      for (int r = 0; r < 4; ++r)
        pa[mt * 16 + qd * 4 + r] = acc[mt][r];
    return;
  }

  // ---------------- windowed + global-key attention ----------------
  const int qc = bid0 & 15, h = (bid0 >> 4) & 15, b = bid0 >> 8;
  const int qs = qc << 8;
  const int qw = qs + wv * 64;
  const size_t bh = (size_t)(b * Hc + h);
  const half_t* qb = qh + bh * Sc * Dc;
  const half_t* kb = kh + bh * Sc * Dc;
  const half_t* vb = vt + bh * Dc * Sc;

  h8 qf[4][2];
#pragma unroll
  for (int qt = 0; qt < 4; ++qt) {
    const half_t* qrow = qb + (size_t)(qw + qt * 16 + mr) * Dc;
    qf[qt][0] = *(const h8*)(qrow + qd * 8);
    qf[qt][1] = *(const h8*)(qrow + 32 + qd * 8);
  }

  int tiles[14];
  int nT = 0;
  tiles[nT++] = 0;
  {
    int lo = qs - Wc; if (lo < Gc) lo = Gc;
    int hi2 = qs + 448; if (hi2 > Sc - 64) hi2 = Sc - 64;
    for (int kp0 = lo; kp0 <= hi2; kp0 += 64) tiles[nT++] = kp0;
  }

  auto stage = [&](int kp0, int bi) {
#pragma unroll
    for (int i = 0; i < 2; ++i) {
      const int seg = wv * 2 + i;
      const int s = seg * 64 + lane;
      const int r = s >> 3;
      const int kc = (s & 7) ^ (r & 7);
      gl_lds16(kb + (size_t)(kp0 + r) * Dc + kc * 8, &Kb[bi][seg * 512]);
      gl_lds16(vb + (size_t)r * Sc + kp0 + kc * 8, &Vb[bi][seg * 512]);
    }
  };

  float m_run[4], l_run[4];
  f4 acc[4][4] = {};
#pragma unroll
  for (int qt = 0; qt < 4; ++qt) { m_run[qt] = -1e30f; l_run[qt] = 0.f; }

  stage(tiles[0], 0);

  for (int t = 0; t < nT; ++t) {
    __syncthreads();
    if (t + 1 < nT) stage(tiles[t + 1], (t + 1) & 1);
    const int kp0 = tiles[t];
    if (t > 0 && (kp0 > qw + 319 || kp0 + 63 < qw - Wc)) continue;

    const half_t* BK = Kb[t & 1];
    const half_t* BV = Vb[t & 1];
    h8 kf[4][2], vf[4][2];
#pragma unroll
    for (int mt = 0; mt < 4; ++mt) {
      const int row = mt * 16 + mr, r7 = row & 7;
      kf[mt][0] = *(const h8*)(BK + (size_t)(row * 8 + (qd ^ r7)) * 8);
      kf[mt][1] = *(const h8*)(BK + (size_t)(row * 8 + ((qd + 4) ^ r7)) * 8);
      vf[mt][0] = *(const h8*)(BV + (size_t)(row * 8 + (qd ^ r7)) * 8);
      vf[mt][1] = *(const h8*)(BV + (size_t)(row * 8 + ((qd + 4) ^ r7)) * 8);
    }
    const bool nomask = (t == 0) || (kp0 >= qw - 193 && kp0 <= qw + 193);

#pragma unroll
    for (int qt = 0; qt < 4; ++qt) {
      f4 sa[4];
#pragma unroll
      for (int mt = 0; mt < 4; ++mt) {
        f4 s = {};
        s = mfma16(kf[mt][0], qf[qt][0], s);
        s = mfma16(kf[mt][1], qf[qt][1], s);
        sa[mt] = s;
      }
      const int q = qw + qt * 16 + mr;
      if (!nomask) {
#pragma unroll
        for (int mt = 0; mt < 4; ++mt)
#pragma unroll
          for (int r = 0; r < 4; ++r) {
            const int kp = kp0 + mt * 16 + qd * 4 + r;
            if (kp < q - Wc || kp > q + Wc) sa[mt][r] = NEGV;
          }
      }
      float tm = -1e30f;
#pragma unroll
      for (int mt = 0; mt < 4; ++mt)
#pragma unroll
        for (int r = 0; r < 4; ++r) tm = fmaxf(tm, sa[mt][r]);
      tm = fmaxf(tm, __shfl_xor(tm, 16));
      tm = fmaxf(tm, __shfl_xor(tm, 32));
      const float mnew = fmaxf(m_run[qt], tm);
      const float alpha = __expf(m_run[qt] - mnew);
      m_run[qt] = mnew;
      float psum = 0.0f;
#pragma unroll
      for (int mt = 0; mt < 4; ++mt) {
        h4 pk;
#pragma unroll
        for (int r = 0; r < 4; ++r) {
          const float p = __expf(sa[mt][r] - mnew);
          psum += p;
          pk[r] = (half_t)p;
        }
        *(h4*)(Pw + mr * PST + mt * 16 + qd * 4) = pk;
      }
      psum += __shfl_xor(psum, 16);
      psum += __shfl_xor(psum, 32);
      l_run[qt] = l_run[qt] * alpha + psum;
#pragma unroll
      for (int mt = 0; mt < 4; ++mt)
#pragma unroll
        for (int r = 0; r < 4; ++r) acc[qt][mt][r] *= alpha;
      const h8 p0 = *(const h8*)(Pw + mr * PST + qd * 8);
      const h8 p1 = *(const h8*)(Pw + mr * PST + 32 + qd * 8);
#pragma unroll
      for (int mt = 0; mt < 4; ++mt) {
        acc[qt][mt] = mfma16(vf[mt][0], p0, acc[qt][mt]);
        acc[qt][mt] = mfma16(vf[mt][1], p1, acc[qt][mt]);
      }
    }
  }

#pragma unroll
  for (int qt = 0; qt < 4; ++qt) {
    const float inv = 1.0f / l_run[qt];
    const int q = qw + qt * 16 + mr;
    half_t* crow = ctx + ((size_t)(b * Sc) + q) * Ec + h * Dc;
#pragma unroll
    for (int mt = 0; mt < 4; ++mt) {
      h4 pk;
#pragma unroll
      for (int r = 0; r < 4; ++r) pk[r] = (half_t)(acc[qt][mt][r] * inv);
      *(h4*)(crow + mt * 16 + qd * 4) = pk;
    }
  }
}

// gq_combine: grid = B*H; thread (q = tid>>2, 16 d's at dg=(tid&3)*16) merges 8 chunks.
__global__ __launch_bounds__(256) void gq_combine(const float* __restrict__ pm,
                                                  const float* __restrict__ pl,
                                                  const float* __restrict__ pacc,
                                                  half_t* __restrict__ ctx) {
  const int h = blockIdx.x & 15, b = blockIdx.x >> 4;
  const size_t bh = (size_t)(b * Hc + h);
  const int q = threadIdx.x >> 2, dg = (threadIdx.x & 3) * 16;
  float m[8];
  float M = -1e30f;
#pragma unroll
  for (int c = 0; c < 8; ++c) {
    m[c] = pm[(bh * 8 + c) * Gc + q];
    M = fmaxf(M, m[c]);
  }
  float denom = 0.f, num[16] = {};
#pragma unroll
  for (int c = 0; c < 8; ++c) {
    const float w = __expf(m[c] - M);
    denom += w * pl[(bh * 8 + c) * Gc + q];
    const float* pa = pacc + ((bh * 8 + c) * Gc + q) * Dc + dg;
#pragma unroll
    for (int j = 0; j < 16; ++j) num[j] += w * pa[j];
  }
  const float inv = 1.0f / denom;
  half_t* crow = ctx + ((size_t)(b * Sc) + q) * Ec + h * Dc + dg;
#pragma unroll
  for (int j = 0; j < 16; ++j) crow[j] = (half_t)(num[j] * inv);
}

// ---------------- host launch ----------------

extern "C" void kernel_launch(void* const* d_in, const int* in_sizes, int n_in,
                              void* d_out, int out_size, void* d_ws, size_t ws_size,
                              hipStream_t stream) {
  const float* x   = (const float*)d_in[0];
  const float* Wq  = (const float*)d_in[2];
  const float* bq  = (const float*)d_in[3];
  const float* Wk  = (const float*)d_in[4];
  const float* bk  = (const float*)d_in[5];
  const float* Wv  = (const float*)d_in[6];
  const float* bv  = (const float*)d_in[7];
  const float* Wqg = (const float*)d_in[8];
  const float* bqg = (const float*)d_in[9];
  const float* Wkg = (const float*)d_in[10];
  const float* bkg = (const float*)d_in[11];
  const float* Wvg = (const float*)d_in[12];
  const float* bvg = (const float*)d_in[13];
  const float* Wo  = (const float*)d_in[14];
  const float* bo  = (const float*)d_in[15];
  float* out = (float*)d_out;

  char* ws = (char*)d_ws;
  size_t off = 0;
  auto alloc = [&](size_t bytes) {
    void* p = ws + off;
    off = (off + bytes + 255) & ~(size_t)255;
    return p;
  };
  const size_t BSE2 = (size_t)Bc * Sc * Ec * 2;
  const size_t W2 = (size_t)Ec * Ec * 2;
  half_t* xh   = (half_t*)alloc(BSE2);
  half_t* Wcat = (half_t*)alloc(W2 * 6);   // q,k,v,kg,vg,qg transposed f16
  half_t* WtO  = (half_t*)alloc(W2);
  half_t* qh   = (half_t*)alloc(BSE2);     // (B,H,S,D) scaled
  half_t* kh   = (half_t*)alloc(BSE2);     // (B,H,S,D)
  half_t* vt   = (half_t*)alloc(BSE2);     // (B,H,D,S)
  half_t* kgh  = (half_t*)alloc(BSE2);     // (B,H,S,D)
  half_t* vgt  = (half_t*)alloc(BSE2);     // (B,H,D,S)
  half_t* qgh  = (half_t*)alloc((size_t)Bc * Hc * Gc * Dc * 2);
  half_t* ctx  = (half_t*)alloc(BSE2);
  float*  pm   = (float*)alloc((size_t)Bc * Hc * 8 * Gc * 4);
  float*  pl   = (float*)alloc((size_t)Bc * Hc * 8 * Gc * 4);
  float*  pacc = (float*)alloc((size_t)Bc * Hc * 8 * Gc * Dc * 4);
  (void)ws_size; (void)in_sizes; (void)n_in; (void)out_size;

  prep<<<4096 + 7 * 256, 256, 0, stream>>>(x, Wq, Wk, Wv, Wkg, Wvg, Wqg, Wo,
                                           xh, Wcat, WtO);

  gemm_proj<<<dim3(40, 33), 256, 0, stream>>>(xh, Wcat, bq, bk, bv, bkg, bvg, bqg,
                                              qh, kh, vt, kgh, vgt, qgh);

  attn_fused<<<512 + 256, 256, 0, stream>>>(qh, kh, vt, qgh, kgh, vgt,
                                            ctx, pm, pl, pacc);

  gq_combine<<<Bc * Hc, 256, 0, stream>>>(pm, pl, pacc, ctx);

  gemm_out<<<dim3(8, 64), 256, 0, stream>>>(ctx, WtO, bo, out);
}